// Round 1
// baseline (16970.839 us; speedup 1.0000x reference)
//
#include <hip/hip_runtime.h>
#include <hip/hip_bf16.h>

typedef float  f32x4  __attribute__((ext_vector_type(4)));
typedef float  f32x16 __attribute__((ext_vector_type(16)));
typedef __bf16 bfrag8 __attribute__((ext_vector_type(8)));
typedef __bf16 bf16x4 __attribute__((ext_vector_type(4)));

#define T_STEPS 1024
#define BB 64
#define II 512
#define HH 512
#define G4 2048
#define NB 64
#define BH (BB*HH)   // 32768 elems

// ---------------- init: h0 fp32 -> h_bufs[0] bf16 ----------------
__global__ void k_init_h(const float* __restrict__ h0, __bf16* __restrict__ hb) {
  int i = blockIdx.x * 256 + threadIdx.x;
  hb[i] = (__bf16)h0[i];
}

// ---------------- phase 1: x_proj = input @ W_ih^T + b_ih + b_hh ----------------
// C[m][g] = sum_k inp[m][k]*Wih[g][k] + bias, M=65536 N=2048 K=512
template<bool XF32>
__global__ __launch_bounds__(256) void k_xproj(
    const float* __restrict__ inp, const float* __restrict__ Wih,
    const float* __restrict__ bih, const float* __restrict__ bhh,
    void* __restrict__ xp_) {
  constexpr int BM = 128, BN = 128, BK = 64, LDK = 72;  // +8 bf16 pad (16B, odd 16B stride)
  __shared__ __bf16 As[BM][LDK];
  __shared__ __bf16 Bs[BN][LDK];
  const int bx = blockIdx.x;
  const int tm = bx >> 4, tn = bx & 15;
  const int m0 = tm * BM, n0 = tn * BN;
  const int tid = threadIdx.x;
  const int lane = tid & 63, w = tid >> 6;
  const int wm = w >> 1, wn = w & 1;       // 2x2 waves, 64x64 per wave
  const int l31 = lane & 31, lhi = lane >> 5;

  f32x16 acc[2][2] = {};

  const int srow = tid >> 2;   // 0..63 (two passes for 128 rows)
  const int sq = tid & 3;      // 16-fp32 (64B) quarter of the 64-wide K strip

  for (int k0 = 0; k0 < 512; k0 += BK) {
    __syncthreads();
    #pragma unroll
    for (int j = 0; j < 2; j++) {
      const int r = srow + 64 * j;
      const float* pa = inp + (size_t)(m0 + r) * II + k0 + sq * 16;
      const float* pb = Wih + (size_t)(n0 + r) * II + k0 + sq * 16;
      #pragma unroll
      for (int i = 0; i < 4; i++) {
        f32x4 va = *(const f32x4*)(pa + 4 * i);
        bf16x4 wa; wa[0]=(__bf16)va[0]; wa[1]=(__bf16)va[1]; wa[2]=(__bf16)va[2]; wa[3]=(__bf16)va[3];
        *(bf16x4*)&As[r][sq * 16 + 4 * i] = wa;
        f32x4 vb = *(const f32x4*)(pb + 4 * i);
        bf16x4 wb; wb[0]=(__bf16)vb[0]; wb[1]=(__bf16)vb[1]; wb[2]=(__bf16)vb[2]; wb[3]=(__bf16)vb[3];
        *(bf16x4*)&Bs[r][sq * 16 + 4 * i] = wb;
      }
    }
    __syncthreads();
    #pragma unroll
    for (int ks = 0; ks < 4; ks++) {
      const int kk = ks * 16 + 8 * lhi;
      bfrag8 af0 = *(const bfrag8*)&As[64 * wm +      l31][kk];
      bfrag8 af1 = *(const bfrag8*)&As[64 * wm + 32 + l31][kk];
      bfrag8 bf0 = *(const bfrag8*)&Bs[64 * wn +      l31][kk];
      bfrag8 bf1 = *(const bfrag8*)&Bs[64 * wn + 32 + l31][kk];
      acc[0][0] = __builtin_amdgcn_mfma_f32_32x32x16_bf16(af0, bf0, acc[0][0], 0, 0, 0);
      acc[0][1] = __builtin_amdgcn_mfma_f32_32x32x16_bf16(af0, bf1, acc[0][1], 0, 0, 0);
      acc[1][0] = __builtin_amdgcn_mfma_f32_32x32x16_bf16(af1, bf0, acc[1][0], 0, 0, 0);
      acc[1][1] = __builtin_amdgcn_mfma_f32_32x32x16_bf16(af1, bf1, acc[1][1], 0, 0, 0);
    }
  }
  #pragma unroll
  for (int a = 0; a < 2; a++)
    #pragma unroll
    for (int b = 0; b < 2; b++) {
      const int col = n0 + 64 * wn + 32 * b + l31;
      const float bias = bih[col] + bhh[col];
      #pragma unroll
      for (int q = 0; q < 16; q++) {
        const int row = m0 + 64 * wm + 32 * a + (q & 3) + 8 * (q >> 2) + 4 * lhi;
        const float v = acc[a][b][q] + bias;
        if constexpr (XF32) ((float*)xp_)[(size_t)row * G4 + col] = v;
        else                ((__bf16*)xp_)[(size_t)row * G4 + col] = (__bf16)v;
      }
    }
}

// ---------------- phase 2: persistent recurrence ----------------
// 64 blocks: bid = rb (batch half, 32 rows) + 2*g (h-col group, 16 cols).
// 4 waves: tt = w&1 selects gate pair ([i|f] or [z|o]); kh = w>>1 selects K half (256).
// W_hh B-fragments permanently in registers; c in registers; h broadcast via
// per-step global bf16 buffers + per-block flags (agent-scope release/acquire).
template<bool XF32>
__global__ __launch_bounds__(256, 1) void k_recur(
    const float* __restrict__ Whh, const float* __restrict__ c0,
    const void* __restrict__ xp_, __bf16* __restrict__ hb,
    int* __restrict__ flags, float* __restrict__ out) {
  const int bid = blockIdx.x;
  const int rb = bid & 1;
  const int g  = bid >> 1;
  const int tid = threadIdx.x;
  const int lane = tid & 63, w = tid >> 6;
  const int tt = w & 1, kh = w >> 1;
  const int l31 = lane & 31, lhi = lane >> 5;

  __shared__ __bf16 hA[32][520];        // 32 rows x 512 K, +8 pad -> 4-way max on b128
  __shared__ float pRed[2][32][32];     // K-half partials from kh=1 waves
  __shared__ float gLds[4][32][16];     // sigmoided gates i/f/z/o

  const int gate = tt * 2 + (l31 >> 4);           // 0..3
  const int gcol = gate * 512 + g * 16 + (l31 & 15);  // global gate column

  // Load W_hh fragments once: B-operand layout col=lane&31, k = 8*(lane>>5)+j
  bfrag8 bw[16];
  #pragma unroll
  for (int ks = 0; ks < 16; ks++) {
    const float* p = Whh + (size_t)gcol * HH + kh * 256 + ks * 16 + 8 * lhi;
    f32x4 v0 = *(const f32x4*)p;
    f32x4 v1 = *(const f32x4*)(p + 4);
    bfrag8 f;
    f[0]=(__bf16)v0[0]; f[1]=(__bf16)v0[1]; f[2]=(__bf16)v0[2]; f[3]=(__bf16)v0[3];
    f[4]=(__bf16)v1[0]; f[5]=(__bf16)v1[1]; f[6]=(__bf16)v1[2]; f[7]=(__bf16)v1[3];
    bw[ks] = f;
  }

  // c ownership: thread e in {tid, tid+256}: local row e>>4, local col e&15
  float creg[2];
  #pragma unroll
  for (int u = 0; u < 2; u++) {
    const int e = tid + 256 * u;
    creg[u] = c0[(size_t)(32 * rb + (e >> 4)) * HH + 16 * g + (e & 15)];
  }

  const int str = w * 8 + (lane >> 3);  // staging row 0..31
  const int sc8 = (lane & 7) * 8;       // staging col start (bf16 elems)

  for (int s = 0; s < T_STEPS; s++) {
    const int t = T_STEPS - 1 - s;
    if (s > 0) {
      int* fl = flags + s * NB;
      for (;;) {
        int v = __hip_atomic_load(fl + lane, __ATOMIC_RELAXED, __HIP_MEMORY_SCOPE_AGENT);
        if (__ballot(v != 0) == ~0ull) break;
      }
      __threadfence();  // acquire: invalidate L1/L2 so h reads see IC data
    }
    // Issue x_proj loads early (independent of h) so latency hides under staging+MFMA.
    f32x16 xv = {};
    if (kh == 0) {
      #pragma unroll
      for (int q = 0; q < 16; q++) {
        const int row = (q & 3) + 8 * (q >> 2) + 4 * lhi;
        const size_t idx = ((size_t)t * BB + 32 * rb + row) * G4 + gcol;
        if constexpr (XF32) xv[q] = ((const float*)xp_)[idx];
        else                xv[q] = (float)((const __bf16*)xp_)[idx];
      }
    }
    // Stage h rows [32*rb, +32) x 512 into LDS (coalesced 16B chunks)
    {
      const __bf16* p = hb + (size_t)s * BH + (size_t)(32 * rb + str) * HH + sc8;
      #pragma unroll
      for (int i = 0; i < 8; i++) {
        bfrag8 v = *(const bfrag8*)(p + 64 * i);
        *(bfrag8*)&hA[str][sc8 + 64 * i] = v;
      }
    }
    __syncthreads();
    // GEMM: this wave's 32x32 tile, K = its 256-half
    f32x16 acc = {};
    #pragma unroll
    for (int ks = 0; ks < 16; ks++) {
      bfrag8 a = *(const bfrag8*)&hA[l31][kh * 256 + ks * 16 + 8 * lhi];
      acc = __builtin_amdgcn_mfma_f32_32x32x16_bf16(a, bw[ks], acc, 0, 0, 0);
    }
    if (kh == 1) {
      #pragma unroll
      for (int q = 0; q < 16; q++) {
        const int row = (q & 3) + 8 * (q >> 2) + 4 * lhi;
        pRed[tt][row][l31] = acc[q];
      }
    }
    __syncthreads();
    if (kh == 0) {
      #pragma unroll
      for (int q = 0; q < 16; q++) {
        const int row = (q & 3) + 8 * (q >> 2) + 4 * lhi;
        const float v = acc[q] + pRed[tt][row][l31] + xv[q];
        gLds[gate][row][l31 & 15] = 1.f / (1.f + __expf(-v));
      }
    }
    __syncthreads();
    // c/h update: all 256 threads, 2 elems each
    #pragma unroll
    for (int u = 0; u < 2; u++) {
      const int e = tid + 256 * u;
      const int lb = e >> 4, lj = e & 15;
      const float iv = gLds[0][lb][lj];
      const float fv = gLds[1][lb][lj];
      const float zv = gLds[2][lb][lj];
      const float ov = gLds[3][lb][lj];
      const float cn = fv * creg[u] + zv - iv;
      creg[u] = cn;
      const float hn = 1.f / (1.f + __expf(-cn)) - ov;
      const int b = 32 * rb + lb, j = 16 * g + lj;
      out[(size_t)t * BH + (size_t)b * HH + j] = hn;
      hb[(size_t)(s + 1) * BH + (size_t)b * HH + j] = (__bf16)hn;
      if (s == T_STEPS - 1) {
        out[(size_t)T_STEPS * BH + (size_t)b * HH + j] = hn;        // h_f
        out[(size_t)T_STEPS * BH + BH + (size_t)b * HH + j] = cn;   // c_f
      }
    }
    __threadfence();    // release: push h writes to device scope
    __syncthreads();    // all threads' fences done before flag
    if (tid == 0)
      __hip_atomic_store(flags + (s + 1) * NB + bid, 1, __ATOMIC_RELEASE,
                         __HIP_MEMORY_SCOPE_AGENT);
  }
}

extern "C" void kernel_launch(void* const* d_in, const int* in_sizes, int n_in,
                              void* d_out, int out_size, void* d_ws, size_t ws_size,
                              hipStream_t stream) {
  (void)in_sizes; (void)n_in; (void)out_size;
  const float* inp = (const float*)d_in[0];
  const float* h0  = (const float*)d_in[1];
  const float* c0  = (const float*)d_in[2];
  const float* Wih = (const float*)d_in[3];
  const float* Whh = (const float*)d_in[4];
  const float* bih = (const float*)d_in[5];
  const float* bhh = (const float*)d_in[6];
  float* out = (float*)d_out;
  char* ws = (char*)d_ws;

  // ws layout: flags @0 (256KB) | h_bufs @1MB (64.1MB bf16) | x_proj @72MB
  int*    flags = (int*)ws;
  __bf16* hb    = (__bf16*)(ws + (1u << 20));
  void*   xp    = (void*)(ws + 0x4800000ull);
  const size_t need_f32 = 0x4800000ull + (size_t)T_STEPS * BB * G4 * 4;
  const bool xf32 = ws_size >= need_f32;

  hipMemsetAsync(flags, 0, (T_STEPS + 1) * NB * sizeof(int), stream);
  k_init_h<<<BH / 256, 256, 0, stream>>>(h0, hb);
  const int gemm_grid = (T_STEPS * BB / 128) * (G4 / 128);  // 8192
  if (xf32) {
    k_xproj<true ><<<gemm_grid, 256, 0, stream>>>(inp, Wih, bih, bhh, xp);
    k_recur<true ><<<NB, 256, 0, stream>>>(Whh, c0, xp, hb, flags, out);
  } else {
    k_xproj<false><<<gemm_grid, 256, 0, stream>>>(inp, Wih, bih, bhh, xp);
    k_recur<false><<<NB, 256, 0, stream>>>(Whh, c0, xp, hb, flags, out);
  }
}

// Round 2
// 6900.329 us; speedup vs baseline: 2.4594x; 2.4594x over previous
//
#include <hip/hip_runtime.h>
#include <hip/hip_bf16.h>

typedef float  f32x2  __attribute__((ext_vector_type(2)));
typedef float  f32x4  __attribute__((ext_vector_type(4)));
typedef float  f32x16 __attribute__((ext_vector_type(16)));
typedef __bf16 bfrag8 __attribute__((ext_vector_type(8)));
typedef __bf16 bf16x4 __attribute__((ext_vector_type(4)));

#define T_STEPS 1024
#define BB 64
#define II 512
#define HH 512
#define G4 2048
#define NB 64
#define BH (BB*HH)   // 32768 elems

static __device__ inline unsigned pack_bf16x2(float a, float b) {
  union { __bf16 h[2]; unsigned u; } v;
  v.h[0] = (__bf16)a; v.h[1] = (__bf16)b;
  return v.u;
}

// ---------------- init: h0 fp32 -> h_bufs[0] bf16 ----------------
__global__ void k_init_h(const float* __restrict__ h0, __bf16* __restrict__ hb) {
  int i = blockIdx.x * 256 + threadIdx.x;
  hb[i] = (__bf16)h0[i];
}

// ---------------- phase 1: x_proj = input @ W_ih^T + b_ih + b_hh ----------------
// C[m][g] = sum_k inp[m][k]*Wih[g][k] + bias, M=65536 N=2048 K=512
template<bool XF32>
__global__ __launch_bounds__(256) void k_xproj(
    const float* __restrict__ inp, const float* __restrict__ Wih,
    const float* __restrict__ bih, const float* __restrict__ bhh,
    void* __restrict__ xp_) {
  constexpr int BM = 128, BN = 128, BK = 64, LDK = 72;  // +8 bf16 pad
  __shared__ __bf16 As[BM][LDK];
  __shared__ __bf16 Bs[BN][LDK];
  const int bx = blockIdx.x;
  const int tm = bx >> 4, tn = bx & 15;
  const int m0 = tm * BM, n0 = tn * BN;
  const int tid = threadIdx.x;
  const int lane = tid & 63, w = tid >> 6;
  const int wm = w >> 1, wn = w & 1;       // 2x2 waves, 64x64 per wave
  const int l31 = lane & 31, lhi = lane >> 5;

  f32x16 acc[2][2] = {};

  const int srow = tid >> 2;   // 0..63 (two passes for 128 rows)
  const int sq = tid & 3;      // 16-fp32 (64B) quarter of the 64-wide K strip

  for (int k0 = 0; k0 < 512; k0 += BK) {
    __syncthreads();
    #pragma unroll
    for (int j = 0; j < 2; j++) {
      const int r = srow + 64 * j;
      const float* pa = inp + (size_t)(m0 + r) * II + k0 + sq * 16;
      const float* pb = Wih + (size_t)(n0 + r) * II + k0 + sq * 16;
      #pragma unroll
      for (int i = 0; i < 4; i++) {
        f32x4 va = *(const f32x4*)(pa + 4 * i);
        bf16x4 wa; wa[0]=(__bf16)va[0]; wa[1]=(__bf16)va[1]; wa[2]=(__bf16)va[2]; wa[3]=(__bf16)va[3];
        *(bf16x4*)&As[r][sq * 16 + 4 * i] = wa;
        f32x4 vb = *(const f32x4*)(pb + 4 * i);
        bf16x4 wb; wb[0]=(__bf16)vb[0]; wb[1]=(__bf16)vb[1]; wb[2]=(__bf16)vb[2]; wb[3]=(__bf16)vb[3];
        *(bf16x4*)&Bs[r][sq * 16 + 4 * i] = wb;
      }
    }
    __syncthreads();
    #pragma unroll
    for (int ks = 0; ks < 4; ks++) {
      const int kk = ks * 16 + 8 * lhi;
      bfrag8 af0 = *(const bfrag8*)&As[64 * wm +      l31][kk];
      bfrag8 af1 = *(const bfrag8*)&As[64 * wm + 32 + l31][kk];
      bfrag8 bf0 = *(const bfrag8*)&Bs[64 * wn +      l31][kk];
      bfrag8 bf1 = *(const bfrag8*)&Bs[64 * wn + 32 + l31][kk];
      acc[0][0] = __builtin_amdgcn_mfma_f32_32x32x16_bf16(af0, bf0, acc[0][0], 0, 0, 0);
      acc[0][1] = __builtin_amdgcn_mfma_f32_32x32x16_bf16(af0, bf1, acc[0][1], 0, 0, 0);
      acc[1][0] = __builtin_amdgcn_mfma_f32_32x32x16_bf16(af1, bf0, acc[1][0], 0, 0, 0);
      acc[1][1] = __builtin_amdgcn_mfma_f32_32x32x16_bf16(af1, bf1, acc[1][1], 0, 0, 0);
    }
  }
  #pragma unroll
  for (int a = 0; a < 2; a++)
    #pragma unroll
    for (int b = 0; b < 2; b++) {
      const int col = n0 + 64 * wn + 32 * b + l31;
      const float bias = bih[col] + bhh[col];
      #pragma unroll
      for (int q = 0; q < 16; q++) {
        const int row = m0 + 64 * wm + 32 * a + (q & 3) + 8 * (q >> 2) + 4 * lhi;
        const float v = acc[a][b][q] + bias;
        if constexpr (XF32) ((float*)xp_)[(size_t)row * G4 + col] = v;
        else                ((__bf16*)xp_)[(size_t)row * G4 + col] = (__bf16)v;
      }
    }
}

// ---------------- phase 2: persistent recurrence ----------------
// 64 blocks: bid = rb (batch half, 32 rows) + 2*g (h-col group, 16 cols).
// 4 waves: tt = w&1 -> gate pair ([i|f] or [z|o]); kh = w>>1 -> K half (256).
// W_hh B-fragments permanently in registers; c in registers.
// Cross-block h exchange: device-scope (sc1) loads/stores through the coherent
// Infinity Cache — NO threadfence (no buffer_wbl2 / buffer_inv per step).
// Ordering: h stores drain (vmcnt(0), implied by __syncthreads) before flag store.
template<bool XF32>
__global__ __launch_bounds__(256, 1) void k_recur(
    const float* __restrict__ Whh, const float* __restrict__ c0,
    const void* __restrict__ xp_, __bf16* __restrict__ hb,
    int* __restrict__ flags, float* __restrict__ out) {
  const int bid = blockIdx.x;
  const int rb = bid & 1;
  const int g  = bid >> 1;
  const int tid = threadIdx.x;
  const int lane = tid & 63, w = tid >> 6;
  const int tt = w & 1, kh = w >> 1;
  const int l31 = lane & 31, lhi = lane >> 5;

  __shared__ __bf16 hA[32][520];        // 32 rows x 512 K, +16B pad
  __shared__ float pRed[2][32][32];     // K-half partials from kh=1 waves
  __shared__ float gLds[4][32][16];     // sigmoided gates i/f/z/o

  const int gate = tt * 2 + (l31 >> 4);               // 0..3 (i,f,z,o)
  const int gcol = gate * 512 + g * 16 + (l31 & 15);  // global gate column

  // W_hh fragments once: B-operand layout col=lane&31, k = 8*(lane>>5)+j
  bfrag8 bw[16];
  #pragma unroll
  for (int ks = 0; ks < 16; ks++) {
    const float* p = Whh + (size_t)gcol * HH + kh * 256 + ks * 16 + 8 * lhi;
    f32x4 v0 = *(const f32x4*)p;
    f32x4 v1 = *(const f32x4*)(p + 4);
    bfrag8 f;
    f[0]=(__bf16)v0[0]; f[1]=(__bf16)v0[1]; f[2]=(__bf16)v0[2]; f[3]=(__bf16)v0[3];
    f[4]=(__bf16)v1[0]; f[5]=(__bf16)v1[1]; f[6]=(__bf16)v1[2]; f[7]=(__bf16)v1[3];
    bw[ks] = f;
  }

  // c ownership: thread owns row lb = tid>>3, adjacent cols c2, c2+1 (packs u32)
  const int lb = tid >> 3, c2 = (tid & 7) * 2;
  const int brow = 32 * rb + lb;        // global batch row
  const int jcol = 16 * g + c2;         // global h col (even)
  f32x2 creg = *(const f32x2*)(c0 + (size_t)brow * HH + jcol);

  const int str = w * 8 + (lane >> 3);  // staging row 0..31
  const int sb  = lane & 7;             // 8B chunk id within row

  for (int s = 0; s < T_STEPS; s++) {
    const int t = T_STEPS - 1 - s;

    // x_proj prefetch: independent of h — issue BEFORE the spin so HBM
    // latency hides under the flag wait.
    f32x16 xv = {};
    if (kh == 0) {
      #pragma unroll
      for (int q = 0; q < 16; q++) {
        const int row = (q & 3) + 8 * (q >> 2) + 4 * lhi;
        const size_t idx = ((size_t)t * BB + 32 * rb + row) * G4 + gcol;
        if constexpr (XF32) xv[q] = ((const float*)xp_)[idx];
        else                xv[q] = (float)((const __bf16*)xp_)[idx];
      }
    }

    if (s > 0) {
      if (w == 0) {   // only wave 0 polls the IC (4x less poll traffic)
        const int* fl = flags + s * NB;
        for (;;) {
          int v = __hip_atomic_load(fl + lane, __ATOMIC_RELAXED, __HIP_MEMORY_SCOPE_AGENT);
          if (__ballot(v != 0) == ~0ull) break;
        }
      }
      __syncthreads();
    }

    // Stage h rows [32*rb, +32) x 512 into LDS via device-scope u64 loads
    // (sc1 bypasses the stale L1/L2, reads the coherent IC).
    {
      const unsigned long long* hrow = (const unsigned long long*)
          (hb + (size_t)s * BH + (size_t)(32 * rb + str) * HH);
      #pragma unroll
      for (int i = 0; i < 16; i++) {
        unsigned long long v = __hip_atomic_load(hrow + sb + 8 * i,
            __ATOMIC_RELAXED, __HIP_MEMORY_SCOPE_AGENT);
        *(unsigned long long*)&hA[str][(sb + 8 * i) * 4] = v;
      }
    }
    __syncthreads();

    // GEMM: this wave's 32x32 tile, K = its 256-half
    f32x16 acc = {};
    #pragma unroll
    for (int ks = 0; ks < 16; ks++) {
      bfrag8 a = *(const bfrag8*)&hA[l31][kh * 256 + ks * 16 + 8 * lhi];
      acc = __builtin_amdgcn_mfma_f32_32x32x16_bf16(a, bw[ks], acc, 0, 0, 0);
    }
    if (kh == 1) {
      #pragma unroll
      for (int q = 0; q < 16; q++) {
        const int row = (q & 3) + 8 * (q >> 2) + 4 * lhi;
        pRed[tt][row][l31] = acc[q];
      }
    }
    __syncthreads();
    if (kh == 0) {
      #pragma unroll
      for (int q = 0; q < 16; q++) {
        const int row = (q & 3) + 8 * (q >> 2) + 4 * lhi;
        const float v = acc[q] + pRed[tt][row][l31] + xv[q];
        gLds[gate][row][l31 & 15] = 1.f / (1.f + __expf(-v));
      }
    }
    __syncthreads();

    // c/h update: thread owns (lb, c2..c2+1)
    {
      const float i0 = gLds[0][lb][c2],     i1 = gLds[0][lb][c2 + 1];
      const float f0 = gLds[1][lb][c2],     f1 = gLds[1][lb][c2 + 1];
      const float z0 = gLds[2][lb][c2],     z1 = gLds[2][lb][c2 + 1];
      const float o0 = gLds[3][lb][c2],     o1 = gLds[3][lb][c2 + 1];
      const float cn0 = f0 * creg[0] + z0 - i0;
      const float cn1 = f1 * creg[1] + z1 - i1;
      creg[0] = cn0; creg[1] = cn1;
      const float hn0 = 1.f / (1.f + __expf(-cn0)) - o0;
      const float hn1 = 1.f / (1.f + __expf(-cn1)) - o1;
      // h broadcast: device-scope packed store -> coherent IC
      unsigned* hp = (unsigned*)(hb + (size_t)(s + 1) * BH + (size_t)brow * HH + jcol);
      __hip_atomic_store(hp, pack_bf16x2(hn0, hn1),
                         __ATOMIC_RELAXED, __HIP_MEMORY_SCOPE_AGENT);
      f32x2 hv; hv[0] = hn0; hv[1] = hn1;
      __builtin_nontemporal_store(hv,
          (f32x2*)(out + (size_t)t * BH + (size_t)brow * HH + jcol));
      if (s == T_STEPS - 1) {
        f32x2 cv; cv[0] = cn0; cv[1] = cn1;
        *(f32x2*)(out + (size_t)T_STEPS * BH + (size_t)brow * HH + jcol) = hv;       // h_f
        *(f32x2*)(out + (size_t)T_STEPS * BH + BH + (size_t)brow * HH + jcol) = cv;  // c_f
      }
    }
    // Drain h stores to the IC before raising the flag. __syncthreads emits
    // s_waitcnt vmcnt(0); the explicit asm makes the ordering robust.
    asm volatile("s_waitcnt vmcnt(0)" ::: "memory");
    __syncthreads();
    if (tid == 0)
      __hip_atomic_store(flags + (s + 1) * NB + bid, 1,
                         __ATOMIC_RELAXED, __HIP_MEMORY_SCOPE_AGENT);
  }
}

extern "C" void kernel_launch(void* const* d_in, const int* in_sizes, int n_in,
                              void* d_out, int out_size, void* d_ws, size_t ws_size,
                              hipStream_t stream) {
  (void)in_sizes; (void)n_in; (void)out_size;
  const float* inp = (const float*)d_in[0];
  const float* h0  = (const float*)d_in[1];
  const float* c0  = (const float*)d_in[2];
  const float* Wih = (const float*)d_in[3];
  const float* Whh = (const float*)d_in[4];
  const float* bih = (const float*)d_in[5];
  const float* bhh = (const float*)d_in[6];
  float* out = (float*)d_out;
  char* ws = (char*)d_ws;

  // ws layout: flags @0 (256KB) | h_bufs @1MB (64.1MB bf16) | x_proj @72MB
  int*    flags = (int*)ws;
  __bf16* hb    = (__bf16*)(ws + (1u << 20));
  void*   xp    = (void*)(ws + 0x4800000ull);
  const size_t need_f32 = 0x4800000ull + (size_t)T_STEPS * BB * G4 * 4;
  const bool xf32 = ws_size >= need_f32;

  hipMemsetAsync(flags, 0, (T_STEPS + 1) * NB * sizeof(int), stream);
  k_init_h<<<BH / 256, 256, 0, stream>>>(h0, hb);
  const int gemm_grid = (T_STEPS * BB / 128) * (G4 / 128);  // 8192
  if (xf32) {
    k_xproj<true ><<<gemm_grid, 256, 0, stream>>>(inp, Wih, bih, bhh, xp);
    k_recur<true ><<<NB, 256, 0, stream>>>(Whh, c0, xp, hb, flags, out);
  } else {
    k_xproj<false><<<gemm_grid, 256, 0, stream>>>(inp, Wih, bih, bhh, xp);
    k_recur<false><<<NB, 256, 0, stream>>>(Whh, c0, xp, hb, flags, out);
  }
}

// Round 3
// 5244.807 us; speedup vs baseline: 3.2357x; 1.3156x over previous
//
#include <hip/hip_runtime.h>
#include <hip/hip_bf16.h>

typedef float  f32x2  __attribute__((ext_vector_type(2)));
typedef float  f32x4  __attribute__((ext_vector_type(4)));
typedef float  f32x16 __attribute__((ext_vector_type(16)));
typedef __bf16 bfrag8 __attribute__((ext_vector_type(8)));
typedef __bf16 bf16x4 __attribute__((ext_vector_type(4)));

#define T_STEPS 1024
#define BB 64
#define II 512
#define HH 512
#define G4 2048
#define NB 64
#define BH (BB*HH)   // 32768 elems

static __device__ inline unsigned short bf16_bits(float f) {
  union { __bf16 h; unsigned short u; } v; v.h = (__bf16)f; return v.u;
}

// ---------------- init: h0 fp32 -> tagged u32 slot 0 (tag = 0) ----------------
__global__ void k_init_h(const float* __restrict__ h0, unsigned* __restrict__ hb) {
  int i = blockIdx.x * 256 + threadIdx.x;
  hb[i] = ((unsigned)bf16_bits(h0[i]) << 16);   // | tag 0
}

// ---------------- phase 1: x_proj = input @ W_ih^T + b_ih + b_hh ----------------
template<bool XF32>
__global__ __launch_bounds__(256) void k_xproj(
    const float* __restrict__ inp, const float* __restrict__ Wih,
    const float* __restrict__ bih, const float* __restrict__ bhh,
    void* __restrict__ xp_) {
  constexpr int BM = 128, BN = 128, BK = 64, LDK = 72;
  __shared__ __bf16 As[BM][LDK];
  __shared__ __bf16 Bs[BN][LDK];
  const int bx = blockIdx.x;
  const int tm = bx >> 4, tn = bx & 15;
  const int m0 = tm * BM, n0 = tn * BN;
  const int tid = threadIdx.x;
  const int lane = tid & 63, w = tid >> 6;
  const int wm = w >> 1, wn = w & 1;
  const int l31 = lane & 31, lhi = lane >> 5;

  f32x16 acc[2][2] = {};

  const int srow = tid >> 2;
  const int sq = tid & 3;

  for (int k0 = 0; k0 < 512; k0 += BK) {
    __syncthreads();
    #pragma unroll
    for (int j = 0; j < 2; j++) {
      const int r = srow + 64 * j;
      const float* pa = inp + (size_t)(m0 + r) * II + k0 + sq * 16;
      const float* pb = Wih + (size_t)(n0 + r) * II + k0 + sq * 16;
      #pragma unroll
      for (int i = 0; i < 4; i++) {
        f32x4 va = *(const f32x4*)(pa + 4 * i);
        bf16x4 wa; wa[0]=(__bf16)va[0]; wa[1]=(__bf16)va[1]; wa[2]=(__bf16)va[2]; wa[3]=(__bf16)va[3];
        *(bf16x4*)&As[r][sq * 16 + 4 * i] = wa;
        f32x4 vb = *(const f32x4*)(pb + 4 * i);
        bf16x4 wb; wb[0]=(__bf16)vb[0]; wb[1]=(__bf16)vb[1]; wb[2]=(__bf16)vb[2]; wb[3]=(__bf16)vb[3];
        *(bf16x4*)&Bs[r][sq * 16 + 4 * i] = wb;
      }
    }
    __syncthreads();
    #pragma unroll
    for (int ks = 0; ks < 4; ks++) {
      const int kk = ks * 16 + 8 * lhi;
      bfrag8 af0 = *(const bfrag8*)&As[64 * wm +      l31][kk];
      bfrag8 af1 = *(const bfrag8*)&As[64 * wm + 32 + l31][kk];
      bfrag8 bf0 = *(const bfrag8*)&Bs[64 * wn +      l31][kk];
      bfrag8 bf1 = *(const bfrag8*)&Bs[64 * wn + 32 + l31][kk];
      acc[0][0] = __builtin_amdgcn_mfma_f32_32x32x16_bf16(af0, bf0, acc[0][0], 0, 0, 0);
      acc[0][1] = __builtin_amdgcn_mfma_f32_32x32x16_bf16(af0, bf1, acc[0][1], 0, 0, 0);
      acc[1][0] = __builtin_amdgcn_mfma_f32_32x32x16_bf16(af1, bf0, acc[1][0], 0, 0, 0);
      acc[1][1] = __builtin_amdgcn_mfma_f32_32x32x16_bf16(af1, bf1, acc[1][1], 0, 0, 0);
    }
  }
  #pragma unroll
  for (int a = 0; a < 2; a++)
    #pragma unroll
    for (int b = 0; b < 2; b++) {
      const int col = n0 + 64 * wn + 32 * b + l31;
      const float bias = bih[col] + bhh[col];
      #pragma unroll
      for (int q = 0; q < 16; q++) {
        const int row = m0 + 64 * wm + 32 * a + (q & 3) + 8 * (q >> 2) + 4 * lhi;
        const float v = acc[a][b][q] + bias;
        if constexpr (XF32) ((float*)xp_)[(size_t)row * G4 + col] = v;
        else                ((__bf16*)xp_)[(size_t)row * G4 + col] = (__bf16)v;
      }
    }
}

// ---------------- phase 2: persistent recurrence, data-as-flag ----------------
// h exchanged as tagged u32 words: (bf16_bits << 16) | step_tag. The tag travels
// with the value in one 4B word -> producer needs NO drain and NO flag; the
// consumer's staging loads ARE the poll. 2-slot ping-pong: safe because a block
// reaches step s+2's store only after observing all tags s+1, which requires
// every block to have finished consuming tag s.
template<bool XF32>
__global__ __launch_bounds__(256, 1) void k_recur(
    const float* __restrict__ Whh, const float* __restrict__ c0,
    const void* __restrict__ xp_, unsigned* __restrict__ hb,
    float* __restrict__ out) {
  const int bid = blockIdx.x;
  const int rb = bid & 1;
  const int g  = bid >> 1;
  const int tid = threadIdx.x;
  const int lane = tid & 63, w = tid >> 6;
  const int tt = w & 1, kh = w >> 1;
  const int l31 = lane & 31, lhi = lane >> 5;

  __shared__ __bf16 hA[32][520];        // 32 rows x 512 K, +16B pad
  __shared__ float pRed[2][32][32];     // K-half partials from kh=1 waves
  __shared__ float gLds[4][32][16];     // sigmoided gates i/f/z/o

  const int gate = tt * 2 + (l31 >> 4);               // 0..3 (i,f,z,o)
  const int gcol = gate * 512 + g * 16 + (l31 & 15);  // global gate column

  // W_hh fragments once: B-operand layout col=lane&31, k = 8*(lane>>5)+j
  bfrag8 bw[16];
  #pragma unroll
  for (int ks = 0; ks < 16; ks++) {
    const float* p = Whh + (size_t)gcol * HH + kh * 256 + ks * 16 + 8 * lhi;
    f32x4 v0 = *(const f32x4*)p;
    f32x4 v1 = *(const f32x4*)(p + 4);
    bfrag8 f;
    f[0]=(__bf16)v0[0]; f[1]=(__bf16)v0[1]; f[2]=(__bf16)v0[2]; f[3]=(__bf16)v0[3];
    f[4]=(__bf16)v1[0]; f[5]=(__bf16)v1[1]; f[6]=(__bf16)v1[2]; f[7]=(__bf16)v1[3];
    bw[ks] = f;
  }

  // c ownership: thread owns row lb = tid>>3, adjacent cols c2, c2+1
  const int lb = tid >> 3, c2 = (tid & 7) * 2;
  const int brow = 32 * rb + lb;        // global batch row
  const int jcol = 16 * g + c2;         // global h col (even)
  f32x2 creg = *(const f32x2*)(c0 + (size_t)brow * HH + jcol);

  const int str = w * 8 + (lane >> 3);  // staging row 0..31
  const int sb  = lane & 7;             // u64 chunk id within row (8 threads/row)

  for (int s = 0; s < T_STEPS; s++) {
    const int t = T_STEPS - 1 - s;

    // x_proj prefetch (independent of h): issue first, consumed 2 barriers later.
    f32x16 xv = {};
    if (kh == 0) {
      #pragma unroll
      for (int q = 0; q < 16; q++) {
        const int row = (q & 3) + 8 * (q >> 2) + 4 * lhi;
        const size_t idx = ((size_t)t * BB + 32 * rb + row) * G4 + gcol;
        if constexpr (XF32) xv[q] = ((const float*)xp_)[idx];
        else                xv[q] = (float)((const __bf16*)xp_)[idx];
      }
    }

    // Poll-stage: reload this thread's 32 u64 until every word carries tag s.
    // Per-lane divergent loop (exec-masked): passed lanes keep their v[].
    const unsigned long long* hrow = (const unsigned long long*)
        (hb + (size_t)(s & 1) * BH + (size_t)(32 * rb + str) * HH);
    const unsigned long long tpat = 0x0000FFFF0000FFFFull;
    const unsigned long long texp = (unsigned long long)s * 0x0000000100000001ull;
    unsigned long long v[32];
    for (;;) {
      int ok = 1;
      #pragma unroll
      for (int i = 0; i < 32; i++)
        v[i] = __hip_atomic_load(hrow + sb + 8 * i,
                                 __ATOMIC_RELAXED, __HIP_MEMORY_SCOPE_AGENT);
      #pragma unroll
      for (int i = 0; i < 32; i++) ok &= ((v[i] & tpat) == texp);
      if (ok) break;
    }
    // Extract bf16 pairs (hi16 of each u32) -> LDS
    #pragma unroll
    for (int i = 0; i < 32; i++) {
      const unsigned lo = (unsigned)v[i], hi = (unsigned)(v[i] >> 32);
      const unsigned packed = (lo >> 16) | (hi & 0xFFFF0000u);
      *(unsigned*)&hA[str][(sb + 8 * i) * 2] = packed;
    }
    __syncthreads();

    // GEMM: this wave's 32x32 tile, K = its 256-half
    f32x16 acc = {};
    #pragma unroll
    for (int ks = 0; ks < 16; ks++) {
      bfrag8 a = *(const bfrag8*)&hA[l31][kh * 256 + ks * 16 + 8 * lhi];
      acc = __builtin_amdgcn_mfma_f32_32x32x16_bf16(a, bw[ks], acc, 0, 0, 0);
    }
    if (kh == 1) {
      #pragma unroll
      for (int q = 0; q < 16; q++) {
        const int row = (q & 3) + 8 * (q >> 2) + 4 * lhi;
        pRed[tt][row][l31] = acc[q];
      }
    }
    __syncthreads();
    if (kh == 0) {
      #pragma unroll
      for (int q = 0; q < 16; q++) {
        const int row = (q & 3) + 8 * (q >> 2) + 4 * lhi;
        const float vv = acc[q] + pRed[tt][row][l31] + xv[q];
        gLds[gate][row][l31 & 15] = 1.f / (1.f + __expf(-vv));
      }
    }
    __syncthreads();

    // c/h update: thread owns (lb, c2..c2+1); store tagged h pair (one u64)
    {
      const float i0 = gLds[0][lb][c2],     i1 = gLds[0][lb][c2 + 1];
      const float f0 = gLds[1][lb][c2],     f1 = gLds[1][lb][c2 + 1];
      const float z0 = gLds[2][lb][c2],     z1 = gLds[2][lb][c2 + 1];
      const float o0 = gLds[3][lb][c2],     o1 = gLds[3][lb][c2 + 1];
      const float cn0 = f0 * creg[0] + z0 - i0;
      const float cn1 = f1 * creg[1] + z1 - i1;
      creg[0] = cn0; creg[1] = cn1;
      const float hn0 = 1.f / (1.f + __expf(-cn0)) - o0;
      const float hn1 = 1.f / (1.f + __expf(-cn1)) - o1;
      const unsigned tag = (unsigned)(s + 1);
      const unsigned plo = ((unsigned)bf16_bits(hn0) << 16) | tag;
      const unsigned phi = ((unsigned)bf16_bits(hn1) << 16) | tag;
      const unsigned long long pv = ((unsigned long long)phi << 32) | plo;
      __hip_atomic_store((unsigned long long*)
          (hb + (size_t)((s + 1) & 1) * BH + (size_t)brow * HH + jcol),
          pv, __ATOMIC_RELAXED, __HIP_MEMORY_SCOPE_AGENT);
      f32x2 hv; hv[0] = hn0; hv[1] = hn1;
      __builtin_nontemporal_store(hv,
          (f32x2*)(out + (size_t)t * BH + (size_t)brow * HH + jcol));
      if (s == T_STEPS - 1) {
        f32x2 cv; cv[0] = cn0; cv[1] = cn1;
        *(f32x2*)(out + (size_t)T_STEPS * BH + (size_t)brow * HH + jcol) = hv;       // h_f
        *(f32x2*)(out + (size_t)T_STEPS * BH + BH + (size_t)brow * HH + jcol) = cv;  // c_f
      }
    }
    // No drain, no flag, no trailing barrier: next step's poll barrier +
    // tag-visibility carry all the ordering.
  }
}

extern "C" void kernel_launch(void* const* d_in, const int* in_sizes, int n_in,
                              void* d_out, int out_size, void* d_ws, size_t ws_size,
                              hipStream_t stream) {
  (void)in_sizes; (void)n_in; (void)out_size;
  const float* inp = (const float*)d_in[0];
  const float* h0  = (const float*)d_in[1];
  const float* c0  = (const float*)d_in[2];
  const float* Wih = (const float*)d_in[3];
  const float* Whh = (const float*)d_in[4];
  const float* bih = (const float*)d_in[5];
  const float* bhh = (const float*)d_in[6];
  float* out = (float*)d_out;
  char* ws = (char*)d_ws;

  // ws layout: hb (2-slot tagged u32, 256 KB) @0 | x_proj @1MB
  unsigned* hb = (unsigned*)ws;
  void*     xp = (void*)(ws + (1u << 20));
  const size_t need_f32 = (1u << 20) + (size_t)T_STEPS * BB * G4 * 4;
  const bool xf32 = ws_size >= need_f32;

  k_init_h<<<BH / 256, 256, 0, stream>>>(h0, hb);
  const int gemm_grid = (T_STEPS * BB / 128) * (G4 / 128);  // 8192
  if (xf32) {
    k_xproj<true ><<<gemm_grid, 256, 0, stream>>>(inp, Wih, bih, bhh, xp);
    k_recur<true ><<<NB, 256, 0, stream>>>(Whh, c0, xp, hb, out);
  } else {
    k_xproj<false><<<gemm_grid, 256, 0, stream>>>(inp, Wih, bih, bhh, xp);
    k_recur<false><<<NB, 256, 0, stream>>>(Whh, c0, xp, hb, out);
  }
}